// Round 8
// baseline (292.807 us; speedup 1.0000x reference)
//
#include <hip/hip_runtime.h>

typedef __attribute__((ext_vector_type(8))) short bf16x8;
typedef __attribute__((ext_vector_type(4))) float f32x4;
typedef __attribute__((ext_vector_type(4))) int   i32x4;
typedef __attribute__((ext_vector_type(4))) unsigned int u32x4;

static __device__ __forceinline__ unsigned short f2bf(float f) {
    unsigned int u = __builtin_bit_cast(unsigned int, f);
    u += 0x7fffu + ((u >> 16) & 1u);          // round-to-nearest-even
    return (unsigned short)(u >> 16);
}
static __device__ __forceinline__ float bf2f(unsigned short h) {
    unsigned int u = ((unsigned int)h) << 16;
    return __builtin_bit_cast(float, u);
}

// ---------------- quantize x -> int8 (per-row scale), PERMUTED channel layout ----------------
// Row byte layout: chunk lg (16B) holds channels [lg*8..+8) in bytes 0..7 and
// [32+lg*8..+8) in bytes 8..15  => one dwordx4 at lg*16 feeds both K=32 MFMA halves.
__global__ void qx_kernel(const float* __restrict__ x, signed char* __restrict__ xq,
                          float* __restrict__ sc, int n) {
    const int m = blockIdx.x * 32 + (threadIdx.x >> 3);
    const int j = threadIdx.x & 7;
    if (m >= n) return;
    const float4* p = reinterpret_cast<const float4*>(x + (size_t)m * 64 + j * 8);
    float4 a = p[0], b = p[1];
    float mx = fmaxf(fmaxf(fmaxf(fabsf(a.x), fabsf(a.y)), fmaxf(fabsf(a.z), fabsf(a.w))),
                     fmaxf(fmaxf(fabsf(b.x), fabsf(b.y)), fmaxf(fabsf(b.z), fabsf(b.w))));
    mx = fmaxf(mx, __shfl_xor(mx, 1));
    mx = fmaxf(mx, __shfl_xor(mx, 2));
    mx = fmaxf(mx, __shfl_xor(mx, 4));
    const float inv = mx > 0.f ? 127.0f / mx : 0.f;
    auto qb = [&](float f, int sh) -> unsigned long long {
        int t = (int)rintf(f * inv);
        t = t < -127 ? -127 : (t > 127 ? 127 : t);
        return ((unsigned long long)(unsigned char)(signed char)t) << sh;
    };
    unsigned long long pk = qb(a.x, 0) | qb(a.y, 8) | qb(a.z, 16) | qb(a.w, 24)
                          | qb(b.x, 32) | qb(b.y, 40) | qb(b.z, 48) | qb(b.w, 56);
    const int dst = (j < 4) ? j * 16 : (j - 4) * 16 + 8;
    *reinterpret_cast<unsigned long long*>(xq + (size_t)m * 64 + dst) = pk;
    if (j == 0) sc[m] = mx * (1.0f / 127.0f);
}

// ---------------- W [k][cin][cout] f32 -> WT [k][cout][cin] bf16, both tensors ----------------
__global__ void cvt_w_kernel(const float* __restrict__ w1, const float* __restrict__ w2,
                             unsigned short* __restrict__ wt1, unsigned short* __restrict__ wt2) {
    int i = blockIdx.x * blockDim.x + threadIdx.x;
    if (i >= 2 * 27 * 4096) return;
    const float* w = (i < 27 * 4096) ? w1 : w2;
    unsigned short* wt = (i < 27 * 4096) ? wt1 : wt2;
    int j = (i < 27 * 4096) ? i : i - 27 * 4096;
    int k = j >> 12;
    int cout = (j >> 6) & 63;
    int cin = j & 63;
    wt[j] = f2bf(w[((size_t)(k * 64 + cin)) * 64 + cout]);
}

// ---------------- gathered conv: i8 A gathered to REGISTERS, bf16 MFMA ----------------
// Block = 64 rows x 64 cols; wave w owns rows w*16..+15, ALL 64 cols (4 col-tiles).
// A: per-lane global_load_dwordx4 of its row's 16 i8 (one 64B line per 4 lanes),
//    expanded in-register to exact bf16. Per-row scale folded per tap into f32 acc.
// B: 8KB bf16 tile staged cooperatively to LDS per tap (XOR-swizzled source), barriers.
// Counted queue: 7 VMEM/wave/tap (2 B-stage + 1 A + 4 scale); depth-2 -> vmcnt(14)/7/0.
__global__ __launch_bounds__(256, 4) void conv_i8a(
    const signed char* __restrict__ xq,   // [n][64] i8 (permuted layout)
    const float* __restrict__ scx,        // [n] row scales (L2-resident)
    const int* __restrict__ nh,           // [n][27]
    const unsigned short* __restrict__ wt,// [27][64][64] bf16 cout-major
    unsigned short* __restrict__ y,       // [n][64] bf16 out
    float* __restrict__ pS, float* __restrict__ pQ, int n)
{
    __shared__ unsigned short Bbuf[3][4096];   // 3 x 8KB B tiles
    __shared__ int lidx[64 * 27];              // 6.9KB

    const int tid  = threadIdx.x;
    const int wid  = tid >> 6;
    const int lane = tid & 63;
    const int lr   = lane & 15;
    const int lg   = lane >> 4;
    const int base = blockIdx.x * 64;

    for (int j = tid; j < 64 * 27; j += 256) {
        int row = j / 27;
        int kk  = j - row * 27;
        int gr  = base + row; if (gr >= n) gr = n - 1;
        lidx[j] = nh[(size_t)gr * 27 + kk];
    }
    __syncthreads();   // vmcnt queue empty entering the pipeline

    // per-lane constants
    const int aoff = (wid * 16 + lr) * 27;                 // A-gather lidx base (row lr of wave)
    const int d0o  = (wid * 16 + lg * 4 + 0) * 27;         // scale lidx bases (C rows lg*4+rg)
    const int d1o  = (wid * 16 + lg * 4 + 1) * 27;
    const int d2o  = (wid * 16 + lg * 4 + 2) * 27;
    const int d3o  = (wid * 16 + lg * 4 + 3) * 27;
    // B staging: lane covers row wid*16+(lane>>3) [+8], 16B slot lane&7, pre-swizzled src
    const int bs   = (wid * 16 + (lane >> 3)) * 64 + (((lane & 7) ^ ((lane >> 3) & 7)) << 3);

    f32x4 acc[4];
    #pragma unroll
    for (int t = 0; t < 4; ++t) acc[t] = (f32x4){0.f, 0.f, 0.f, 0.f};
    const f32x4 fz = (f32x4){0.f, 0.f, 0.f, 0.f};

    i32x4 RAa, RAb, RAc;
    float Da0,Da1,Da2,Da3, Db0,Db1,Db2,Db3, Dc0,Dc1,Dc2,Dc3;

#define ISSUE(kk, BUF, RA, D0, D1, D2, D3) do {                                       \
        __builtin_amdgcn_global_load_lds(                                             \
            (const __attribute__((address_space(1))) unsigned int*)(wt + (size_t)(kk)*4096 + bs), \
            (__attribute__((address_space(3))) unsigned int*)(&Bbuf[BUF][wid * 1024]), 16, 0, 0); \
        __builtin_amdgcn_global_load_lds(                                             \
            (const __attribute__((address_space(1))) unsigned int*)(wt + (size_t)(kk)*4096 + bs + 512), \
            (__attribute__((address_space(3))) unsigned int*)(&Bbuf[BUF][wid * 1024 + 512]), 16, 0, 0); \
        RA = *reinterpret_cast<const i32x4*>(xq + (size_t)lidx[aoff + (kk)] * 64 + (lg << 4)); \
        D0 = scx[lidx[d0o + (kk)]];                                                   \
        D1 = scx[lidx[d1o + (kk)]];                                                   \
        D2 = scx[lidx[d2o + (kk)]];                                                   \
        D3 = scx[lidx[d3o + (kk)]];                                                   \
    } while (0)

#define EXP4(W, O0, O1) do {                                                          \
        int w_ = (W);                                                                 \
        float f0_ = (float)((w_ << 24) >> 24);                                        \
        float f1_ = (float)((w_ << 16) >> 24);                                        \
        float f2_ = (float)((w_ << 8) >> 24);                                         \
        float f3_ = (float)(w_ >> 24);                                                \
        O0 = (__builtin_bit_cast(unsigned int, f0_) >> 16) | (__builtin_bit_cast(unsigned int, f1_) & 0xffff0000u); \
        O1 = (__builtin_bit_cast(unsigned int, f2_) >> 16) | (__builtin_bit_cast(unsigned int, f3_) & 0xffff0000u); \
    } while (0)

#define PHASE(BUF, RA, D0, D1, D2, D3, VMSTR) do {                                    \
        asm volatile("s_waitcnt " VMSTR ::: "memory");                                \
        __builtin_amdgcn_s_barrier();                                                 \
        __builtin_amdgcn_sched_barrier(0);                                            \
        unsigned int e0,e1,e2,e3,e4,e5,e6,e7;                                         \
        EXP4(RA[0], e0, e1); EXP4(RA[1], e2, e3);                                     \
        EXP4(RA[2], e4, e5); EXP4(RA[3], e6, e7);                                     \
        u32x4 ah0_ = (u32x4){e0,e1,e2,e3};                                            \
        u32x4 ah1_ = (u32x4){e4,e5,e6,e7};                                            \
        bf16x8 Ah0 = __builtin_bit_cast(bf16x8, ah0_);                                \
        bf16x8 Ah1 = __builtin_bit_cast(bf16x8, ah1_);                                \
        const unsigned short* Bt = &Bbuf[BUF][0];                                     \
        _Pragma("unroll")                                                             \
        for (int ct = 0; ct < 4; ++ct) {                                              \
            const int br_ = (ct * 16 + lr) * 64;                                      \
            bf16x8 B0 = *reinterpret_cast<const bf16x8*>(&Bt[br_ + ((lg ^ (lr & 7)) << 3)]);        \
            bf16x8 B1 = *reinterpret_cast<const bf16x8*>(&Bt[br_ + (((4 + lg) ^ (lr & 7)) << 3)]);  \
            f32x4 Sf = __builtin_amdgcn_mfma_f32_16x16x32_bf16(Ah0, B0, fz, 0, 0, 0); \
            Sf = __builtin_amdgcn_mfma_f32_16x16x32_bf16(Ah1, B1, Sf, 0, 0, 0);       \
            acc[ct][0] += Sf[0] * D0;                                                 \
            acc[ct][1] += Sf[1] * D1;                                                 \
            acc[ct][2] += Sf[2] * D2;                                                 \
            acc[ct][3] += Sf[3] * D3;                                                 \
        }                                                                             \
        asm volatile("s_waitcnt lgkmcnt(0)" ::: "memory");                            \
        __builtin_amdgcn_sched_barrier(0);                                            \
        __builtin_amdgcn_s_barrier();                                                 \
    } while (0)

    // prologue: taps 0,1 in flight (14 VMEM ops/wave)
    ISSUE(0, 0, RAa, Da0, Da1, Da2, Da3);
    __builtin_amdgcn_sched_barrier(0);
    ISSUE(1, 1, RAb, Db0, Db1, Db2, Db3);
    __builtin_amdgcn_sched_barrier(0);

    #pragma unroll 1
    for (int k = 0; k < 24; k += 3) {
        ISSUE(k + 2, 2, RAc, Dc0, Dc1, Dc2, Dc3);
        PHASE(0, RAa, Da0, Da1, Da2, Da3, "vmcnt(14)");
        ISSUE(k + 3, 0, RAa, Da0, Da1, Da2, Da3);
        PHASE(1, RAb, Db0, Db1, Db2, Db3, "vmcnt(14)");
        ISSUE(k + 4, 1, RAb, Db0, Db1, Db2, Db3);
        PHASE(2, RAc, Dc0, Dc1, Dc2, Dc3, "vmcnt(14)");
    }
    // tail: taps 24,25 in flight
    ISSUE(26, 2, RAc, Dc0, Dc1, Dc2, Dc3);
    PHASE(0, RAa, Da0, Da1, Da2, Da3, "vmcnt(14)");
    PHASE(1, RAb, Db0, Db1, Db2, Db3, "vmcnt(7)");
    PHASE(2, RAc, Dc0, Dc1, Dc2, Dc3, "vmcnt(0)");
#undef ISSUE
#undef PHASE
#undef EXP4

    // ---- per-channel partial stats (col = ct*16+lr, rows = wid*16+lg*4+rg) ----
    float s1[4] = {0.f,0.f,0.f,0.f}, s2[4] = {0.f,0.f,0.f,0.f};
    #pragma unroll
    for (int ct = 0; ct < 4; ++ct) {
        #pragma unroll
        for (int rg = 0; rg < 4; ++rg) {
            const int row = base + wid * 16 + lg * 4 + rg;
            if (row < n) {
                const float v = acc[ct][rg];
                s1[ct] += v;
                s2[ct] += v * v;
            }
        }
    }
    #pragma unroll
    for (int ct = 0; ct < 4; ++ct) {
        s1[ct] += __shfl_xor(s1[ct], 16); s1[ct] += __shfl_xor(s1[ct], 32);
        s2[ct] += __shfl_xor(s2[ct], 16); s2[ct] += __shfl_xor(s2[ct], 32);
    }
    // scratch reuse (all gathers/reads retired: last PHASE ended vmcnt(0)+lgkm(0)+barrier)
    unsigned short* yt = &Bbuf[0][0];            // 8KB transpose buffer
    float* fs = reinterpret_cast<float*>(&Bbuf[2][0]);   // 2KB stats scratch
    if (lane < 16) {
        #pragma unroll
        for (int ct = 0; ct < 4; ++ct) {
            fs[(ct * 16 + lr) * 4 + wid]       = s1[ct];
            fs[256 + (ct * 16 + lr) * 4 + wid] = s2[ct];
        }
    }
    #pragma unroll
    for (int ct = 0; ct < 4; ++ct) {
        #pragma unroll
        for (int rg = 0; rg < 4; ++rg) {
            const int row = wid * 16 + lg * 4 + rg;               // block-local
            const int ch  = (ct * 2 + (lr >> 3)) ^ (row & 7);     // swizzled 16B chunk
            yt[row * 64 + ch * 8 + (lr & 7)] = f2bf(acc[ct][rg]);
        }
    }
    __syncthreads();
    {
        const int r0 = tid >> 3;          // 0..31
        const int j  = tid & 7;
        const int g0 = base + r0;
        const int g1 = base + 32 + r0;
        bf16x8 v0 = *reinterpret_cast<const bf16x8*>(&yt[r0 * 64 + ((j ^ (r0 & 7)) * 8)]);
        if (g0 < n) *reinterpret_cast<bf16x8*>(&y[(size_t)g0 * 64 + j * 8]) = v0;
        bf16x8 v1 = *reinterpret_cast<const bf16x8*>(&yt[(32 + r0) * 64 + ((j ^ (r0 & 7)) * 8)]);
        if (g1 < n) *reinterpret_cast<bf16x8*>(&y[(size_t)g1 * 64 + j * 8]) = v1;
    }
    if (tid < 64) {
        const float S = fs[tid * 4] + fs[tid * 4 + 1] + fs[tid * 4 + 2] + fs[tid * 4 + 3];
        const float Q = fs[256 + tid * 4] + fs[256 + tid * 4 + 1] + fs[256 + tid * 4 + 2] + fs[256 + tid * 4 + 3];
        pS[(size_t)tid * gridDim.x + blockIdx.x] = S;
        pQ[(size_t)tid * gridDim.x + blockIdx.x] = Q;
    }
}

// ---------------- BN finalize: parallel reduce of partials ----------------
__global__ __launch_bounds__(256) void bn_stats_kernel(
        const float* __restrict__ pS, const float* __restrict__ pQ,
        const float* __restrict__ gamma, const float* __restrict__ beta,
        float* __restrict__ bnp, int nb, float invN) {
    const int c = blockIdx.x;
    const int tid = threadIdx.x;
    float S = 0.f, Q = 0.f;
    for (int b = tid; b < nb; b += 256) {
        S += pS[(size_t)c * nb + b];
        Q += pQ[(size_t)c * nb + b];
    }
    #pragma unroll
    for (int o = 1; o < 64; o <<= 1) {
        S += __shfl_xor(S, o);
        Q += __shfl_xor(Q, o);
    }
    __shared__ float sh[8];
    if ((tid & 63) == 0) { sh[(tid >> 6) * 2] = S; sh[(tid >> 6) * 2 + 1] = Q; }
    __syncthreads();
    if (tid == 0) {
        S = sh[0] + sh[2] + sh[4] + sh[6];
        Q = sh[1] + sh[3] + sh[5] + sh[7];
        const float mean = S * invN;
        const float var  = Q * invN - mean * mean;
        const float sc   = gamma[c] * rsqrtf(var + 1e-5f);
        bnp[c]      = sc;
        bnp[64 + c] = beta[c] - mean * sc;
    }
}

// ---------------- BN+ReLU+quantize -> int8 (permuted layout) + per-row scale ----------------
__global__ void qbn_kernel(const unsigned short* __restrict__ y, const float* __restrict__ bnp,
                           signed char* __restrict__ yq, float* __restrict__ sc, int n) {
    const int m = blockIdx.x * 32 + (threadIdx.x >> 3);
    const int j = threadIdx.x & 7;
    if (m >= n) return;
    bf16x8 v = *reinterpret_cast<const bf16x8*>(y + (size_t)m * 64 + j * 8);
    float f[8];
    #pragma unroll
    for (int e = 0; e < 8; ++e) {
        const int c = j * 8 + e;
        float t = bf2f((unsigned short)v[e]) * bnp[c] + bnp[64 + c];
        f[e] = fmaxf(t, 0.f);
    }
    float mx = fmaxf(fmaxf(fmaxf(f[0], f[1]), fmaxf(f[2], f[3])),
                     fmaxf(fmaxf(f[4], f[5]), fmaxf(f[6], f[7])));
    mx = fmaxf(mx, __shfl_xor(mx, 1));
    mx = fmaxf(mx, __shfl_xor(mx, 2));
    mx = fmaxf(mx, __shfl_xor(mx, 4));
    const float inv = mx > 0.f ? 127.0f / mx : 0.f;
    unsigned long long pk = 0;
    #pragma unroll
    for (int e = 0; e < 8; ++e) {
        int t = (int)rintf(f[e] * inv);
        t = t < -127 ? -127 : (t > 127 ? 127 : t);
        pk |= ((unsigned long long)(unsigned char)(signed char)t) << (8 * e);
    }
    const int dst = (j < 4) ? j * 16 : (j - 4) * 16 + 8;
    *reinterpret_cast<unsigned long long*>(yq + (size_t)m * 64 + dst) = pk;
    if (j == 0) sc[m] = mx * (1.0f / 127.0f);
}

// ---------------- final: BN2 + residual + ReLU -> f32 out, plus depth ----------------
__global__ void final_kernel(const unsigned short* __restrict__ y2, const float* __restrict__ x,
                             const float* __restrict__ bnp, const int* __restrict__ depth,
                             float* __restrict__ out, int total8, int n) {
    int i = blockIdx.x * blockDim.x + threadIdx.x;
    if (i == 0) out[(size_t)n * 64] = (float)depth[0];
    if (i >= total8) return;
    bf16x8 v = reinterpret_cast<const bf16x8*>(y2)[i];
    const float4* xp = reinterpret_cast<const float4*>(x) + (size_t)i * 2;
    float4 xa = xp[0], xbv = xp[1];
    int c0 = (i * 8) & 63;
    float r[8];
    #pragma unroll
    for (int j = 0; j < 8; ++j)
        r[j] = bf2f((unsigned short)v[j]) * bnp[c0 + j] + bnp[64 + c0 + j];
    r[0] += xa.x;  r[1] += xa.y;  r[2] += xa.z;  r[3] += xa.w;
    r[4] += xbv.x; r[5] += xbv.y; r[6] += xbv.z; r[7] += xbv.w;
    float4* op = reinterpret_cast<float4*>(out) + (size_t)i * 2;
    float4 o0 = {fmaxf(r[0], 0.f), fmaxf(r[1], 0.f), fmaxf(r[2], 0.f), fmaxf(r[3], 0.f)};
    float4 o1 = {fmaxf(r[4], 0.f), fmaxf(r[5], 0.f), fmaxf(r[6], 0.f), fmaxf(r[7], 0.f)};
    op[0] = o0;
    op[1] = o1;
}

extern "C" void kernel_launch(void* const* d_in, const int* in_sizes, int n_in,
                              void* d_out, int out_size, void* d_ws, size_t ws_size,
                              hipStream_t stream) {
    const float* x     = (const float*)d_in[0];
    const int*   neigh = (const int*)d_in[1];
    const int*   depth = (const int*)d_in[2];
    const float* W1    = (const float*)d_in[3];
    const float* g1    = (const float*)d_in[4];
    const float* b1    = (const float*)d_in[5];
    const float* W2    = (const float*)d_in[6];
    const float* g2    = (const float*)d_in[7];
    const float* b2    = (const float*)d_in[8];
    float* out = (float*)d_out;

    const int n      = in_sizes[0] / 64;   // 200000
    const int total8 = in_sizes[0] / 8;
    const int nb     = (n + 63) / 64;      // conv grid (3125)

    char* ws = (char*)d_ws;
    size_t off = 0;
    auto carve = [&](size_t bytes) -> char* {
        char* p = ws + off;
        off += (bytes + 255) & ~((size_t)255);
        return p;
    };
    signed char*    xq   = (signed char*)carve((size_t)n * 64);       // also reused as yq
    float*          scx  = (float*)carve((size_t)n * 4);              // also reused as scy
    unsigned short* y1   = (unsigned short*)carve((size_t)n * 64 * 2);// also reused as y2
    unsigned short* w1t  = (unsigned short*)carve(27 * 4096 * 2);
    unsigned short* w2t  = (unsigned short*)carve(27 * 4096 * 2);
    float*          pS   = (float*)carve((size_t)nb * 64 * 4);
    float*          pQ   = (float*)carve((size_t)nb * 64 * 4);
    float*          bnp1 = (float*)carve(128 * 4);
    float*          bnp2 = (float*)carve(128 * 4);

    const int gq  = (n + 31) / 32;                  // 6250
    const int gw  = (2 * 27 * 4096 + 255) / 256;    // 864
    const int gx  = (total8 + 255) / 256;           // 6250
    const float invN = 1.0f / (float)n;

    qx_kernel<<<gq, 256, 0, stream>>>(x, xq, scx, n);
    cvt_w_kernel<<<gw, 256, 0, stream>>>(W1, W2, w1t, w2t);

    conv_i8a<<<nb, 256, 0, stream>>>(xq, scx, neigh, w1t, y1, pS, pQ, n);
    bn_stats_kernel<<<64, 256, 0, stream>>>(pS, pQ, g1, b1, bnp1, nb, invN);
    qbn_kernel<<<gq, 256, 0, stream>>>(y1, bnp1, xq, scx, n);   // xq/scx reused as yq/scy

    conv_i8a<<<nb, 256, 0, stream>>>(xq, scx, neigh, w2t, y1, pS, pQ, n);  // y1 reused as y2
    bn_stats_kernel<<<64, 256, 0, stream>>>(pS, pQ, g2, b2, bnp2, nb, invN);
    final_kernel<<<gx, 256, 0, stream>>>(y1, x, bnp2, depth, out, total8, n);
}

// Round 9
// 277.787 us; speedup vs baseline: 1.0541x; 1.0541x over previous
//
#include <hip/hip_runtime.h>

typedef __attribute__((ext_vector_type(8))) short bf16x8;
typedef __attribute__((ext_vector_type(4))) float f32x4;

static __device__ __forceinline__ unsigned short f2bf(float f) {
    unsigned int u = __builtin_bit_cast(unsigned int, f);
    u += 0x7fffu + ((u >> 16) & 1u);          // round-to-nearest-even
    return (unsigned short)(u >> 16);
}
static __device__ __forceinline__ float bf2f(unsigned short h) {
    unsigned int u = ((unsigned int)h) << 16;
    return __builtin_bit_cast(float, u);
}

// ---------------- prep: x->bf16 and W->WT bf16, single launch ----------------
__global__ void cvt_xw_kernel(const float* __restrict__ x, unsigned short* __restrict__ xb, int total8, int gx,
                              const float* __restrict__ w1, const float* __restrict__ w2,
                              unsigned short* __restrict__ wt1, unsigned short* __restrict__ wt2) {
    if ((int)blockIdx.x < gx) {
        int i = blockIdx.x * 256 + threadIdx.x;
        if (i >= total8) return;
        const float4* p = reinterpret_cast<const float4*>(x) + (size_t)i * 2;
        float4 a = p[0], b = p[1];
        bf16x8 o;
        o[0] = (short)f2bf(a.x); o[1] = (short)f2bf(a.y); o[2] = (short)f2bf(a.z); o[3] = (short)f2bf(a.w);
        o[4] = (short)f2bf(b.x); o[5] = (short)f2bf(b.y); o[6] = (short)f2bf(b.z); o[7] = (short)f2bf(b.w);
        reinterpret_cast<bf16x8*>(xb)[i] = o;
    } else {
        int i = (blockIdx.x - gx) * 256 + threadIdx.x;
        if (i >= 2 * 27 * 4096) return;
        const float* w = (i < 27 * 4096) ? w1 : w2;
        unsigned short* wt = (i < 27 * 4096) ? wt1 : wt2;
        int j = (i < 27 * 4096) ? i : i - 27 * 4096;
        int k = j >> 12;
        int cout = (j >> 6) & 63;
        int cin = j & 63;
        wt[j] = f2bf(w[((size_t)(k * 64 + cin)) * 64 + cout]);
    }
}

// ---------------- gathered GEMM (octree conv), depth-2, rolled modulo-scheduled ----------------
// Block = 64 rows x 64 cols. 4 waves; wave w owns col-quarter w*16..w*16+15.
// 3 LDS A-buffers + 3 named B-reg pairs; prefetch distance 2. ISSUE = 4 VMEM ops
// (2 B-frag loads then 2 global_load_lds); steady-state wait = vmcnt(8); tail 8/4/0.
// Loop stays ROLLED (rounds 4/5 showed full unroll kills I-cache).
// Epilogue: LDS-transpose (XOR-chunk swizzle) -> coalesced 16B/lane y stores.
// NOTE (rounds 3-8): conv is pinned at FETCH ~303MB @ ~2.35TB/s -- random 128B-line
// miss-service saturation, invariant across schedules; bf16 rows = 1 full line is
// already byte-optimal (round 8: sub-line i8 requests did NOT reduce line fetches).
__global__ __launch_bounds__(256, 5) void conv_mfma(
    const unsigned short* __restrict__ xb,   // [n][64] bf16
    const int* __restrict__ nh,              // [n][27] neighbor indices
    const unsigned short* __restrict__ wt,   // [27][64][64] bf16 (cout-major)
    unsigned short* __restrict__ y,          // [n][64] bf16 (raw conv out)
    float* __restrict__ pS,                  // [64][grid] transposed partials
    float* __restrict__ pQ,                  // [64][grid]
    int n)
{
    __shared__ unsigned short Atile[3][4096];   // 3 x (64 rows x 64 shorts) = 24 KB
    __shared__ int lidx[27 * 64];               // neighbor indices (6.9 KB)

    const int tid  = threadIdx.x;
    const int wid  = tid >> 6;
    const int lane = tid & 63;
    const int lr   = lane & 15;
    const int lg   = lane >> 4;
    const int base = blockIdx.x * 64;

    // stage neighbor indices; after this, idx reads are LDS-only (out of vmcnt queue)
    for (int j = tid; j < 27 * 64; j += 256) {
        int row = j / 27;
        int kk  = j - row * 27;
        int gr  = base + row; if (gr >= n) gr = n - 1;
        lidx[j] = nh[(size_t)gr * 27 + kk];
    }
    __syncthreads();   // full drain: vmcnt queue empty entering the pipeline

    // staging geometry: rows (tid>>3) [+32], 16B slot (tid&7), XOR-swizzled source
    const int srow = tid >> 3;
    const int xoff = ((tid & 7) ^ (srow & 7)) * 8;
    const int so0  = srow * 27;
    const int so1  = (srow + 32) * 27;

    f32x4 acc[4];
    #pragma unroll
    for (int t = 0; t < 4; ++t) acc[t] = (f32x4){0.f, 0.f, 0.f, 0.f};

    const unsigned short* wB = wt + (wid * 16 + lr) * 64 + lg * 8;
    bf16x8 Ba0, Ba1, Bb0, Bb1, Bc0, Bc1;   // 3 named B-pairs: compile-time, no arrays

#define ISSUE(kk, BUF, B0, B1) do {                                                   \
        const int i0_ = lidx[so0 + (kk)];                                             \
        const int i1_ = lidx[so1 + (kk)];                                             \
        B0 = *reinterpret_cast<const bf16x8*>(wB + (size_t)(kk) * 4096);              \
        B1 = *reinterpret_cast<const bf16x8*>(wB + (size_t)(kk) * 4096 + 32);         \
        __builtin_amdgcn_global_load_lds(                                             \
            (const __attribute__((address_space(1))) unsigned int*)(xb + (size_t)i0_ * 64 + xoff), \
            (__attribute__((address_space(3))) unsigned int*)(&Atile[BUF][wid * 512]), 16, 0, 0);    \
        __builtin_amdgcn_global_load_lds(                                             \
            (const __attribute__((address_space(1))) unsigned int*)(xb + (size_t)i1_ * 64 + xoff), \
            (__attribute__((address_space(3))) unsigned int*)(&Atile[BUF][2048 + wid * 512]), 16, 0, 0); \
    } while (0)

#define PHASE(BUF, B0, B1, VMSTR) do {                                                \
        asm volatile("s_waitcnt " VMSTR ::: "memory");                                \
        __builtin_amdgcn_s_barrier();                                                 \
        __builtin_amdgcn_sched_barrier(0);                                            \
        const unsigned short* At = &Atile[BUF][0];                                    \
        _Pragma("unroll")                                                             \
        for (int t = 0; t < 4; ++t) {                                                 \
            const int row_ = t * 16 + lr;                                             \
            const int sw_  = (row_ & 7) * 8;                                          \
            bf16x8 A0 = *reinterpret_cast<const bf16x8*>(&At[row_ * 64 + ((lg * 8) ^ sw_)]);        \
            bf16x8 A1 = *reinterpret_cast<const bf16x8*>(&At[row_ * 64 + (((4 + lg) * 8) ^ sw_)]);  \
            acc[t] = __builtin_amdgcn_mfma_f32_16x16x32_bf16(A0, B0, acc[t], 0, 0, 0); \
            acc[t] = __builtin_amdgcn_mfma_f32_16x16x32_bf16(A1, B1, acc[t], 0, 0, 0); \
        }                                                                             \
        asm volatile("s_waitcnt lgkmcnt(0)" ::: "memory");                            \
        __builtin_amdgcn_sched_barrier(0);                                            \
        __builtin_amdgcn_s_barrier();                                                 \
    } while (0)

    // prologue: taps 0,1 in flight (8 VMEM ops)
    ISSUE(0, 0, Ba0, Ba1);
    ISSUE(1, 1, Bb0, Bb1);

    #pragma unroll 1
    for (int k = 0; k < 24; k += 3) {
        ISSUE(k + 2, 2, Bc0, Bc1);
        PHASE(0, Ba0, Ba1, "vmcnt(8)");    // retire tap k; k+1,k+2 in flight
        ISSUE(k + 3, 0, Ba0, Ba1);
        PHASE(1, Bb0, Bb1, "vmcnt(8)");
        ISSUE(k + 4, 1, Bb0, Bb1);
        PHASE(2, Bc0, Bc1, "vmcnt(8)");
    }
    // tail: taps 24,25 in flight
    ISSUE(26, 2, Bc0, Bc1);
    PHASE(0, Ba0, Ba1, "vmcnt(8)");
    PHASE(1, Bb0, Bb1, "vmcnt(4)");
    PHASE(2, Bc0, Bc1, "vmcnt(0)");
#undef ISSUE
#undef PHASE

    // ---- per-channel partial stats from accumulators ----
    float s1 = 0.f, s2 = 0.f;
    #pragma unroll
    for (int t = 0; t < 4; ++t) {
        #pragma unroll
        for (int rg = 0; rg < 4; ++rg) {
            const int row = base + t * 16 + lg * 4 + rg;   // C/D: row=(lane>>4)*4+reg
            if (row < n) {
                const float v = acc[t][rg];
                s1 += v;
                s2 += v * v;
            }
        }
    }
    s1 += __shfl_xor(s1, 16); s1 += __shfl_xor(s1, 32);
    s2 += __shfl_xor(s2, 16); s2 += __shfl_xor(s2, 32);
    if (lane < 16) {
        const int ch = wid * 16 + lane;
        pS[(size_t)ch * gridDim.x + blockIdx.x] = s1;
        pQ[(size_t)ch * gridDim.x + blockIdx.x] = s2;
    }

    // ---- y store: transpose through LDS (chunk-XOR swizzle), coalesced 16B/lane ----
    // last PHASE ended with lgkmcnt(0)+barrier -> Atile dead, safe to reuse.
    unsigned short* yt = &Atile[0][0];   // [64 rows][64 shorts]
    #pragma unroll
    for (int t = 0; t < 4; ++t) {
        #pragma unroll
        for (int rg = 0; rg < 4; ++rg) {
            const int row = t * 16 + lg * 4 + rg;                 // block-local row
            const int ch  = (wid * 2 + (lr >> 3)) ^ (row & 7);    // swizzled 16B chunk
            yt[row * 64 + ch * 8 + (lr & 7)] = f2bf(acc[t][rg]);
        }
    }
    __syncthreads();
    {
        const int r0 = tid >> 3;          // 0..31
        const int j  = tid & 7;           // 16B chunk within row
        const int g0 = base + r0;
        const int g1 = base + 32 + r0;
        bf16x8 v0 = *reinterpret_cast<const bf16x8*>(&yt[r0 * 64 + ((j ^ (r0 & 7)) * 8)]);
        if (g0 < n) *reinterpret_cast<bf16x8*>(&y[(size_t)g0 * 64 + j * 8]) = v0;
        bf16x8 v1 = *reinterpret_cast<const bf16x8*>(&yt[(32 + r0) * 64 + ((j ^ (r0 & 7)) * 8)]);
        if (g1 < n) *reinterpret_cast<bf16x8*>(&y[(size_t)g1 * 64 + j * 8]) = v1;
    }
}

// ---------------- BN finalize: parallel reduce of partials ----------------
__global__ __launch_bounds__(256) void bn_stats_kernel(
        const float* __restrict__ pS, const float* __restrict__ pQ,
        const float* __restrict__ gamma, const float* __restrict__ beta,
        float* __restrict__ bnp, int nb, float invN) {
    const int c = blockIdx.x;          // channel
    const int tid = threadIdx.x;
    float S = 0.f, Q = 0.f;
    for (int b = tid; b < nb; b += 256) {
        S += pS[(size_t)c * nb + b];
        Q += pQ[(size_t)c * nb + b];
    }
    #pragma unroll
    for (int o = 1; o < 64; o <<= 1) {
        S += __shfl_xor(S, o);
        Q += __shfl_xor(Q, o);
    }
    __shared__ float sh[8];
    if ((tid & 63) == 0) { sh[(tid >> 6) * 2] = S; sh[(tid >> 6) * 2 + 1] = Q; }
    __syncthreads();
    if (tid == 0) {
        S = sh[0] + sh[2] + sh[4] + sh[6];
        Q = sh[1] + sh[3] + sh[5] + sh[7];
        const float mean = S * invN;
        const float var  = Q * invN - mean * mean;
        const float sc   = gamma[c] * rsqrtf(var + 1e-5f);
        bnp[c]      = sc;
        bnp[64 + c] = beta[c] - mean * sc;
    }
}

// ---------------- BN+ReLU -> bf16 (input of conv2) ----------------
__global__ void bn_relu_kernel(const unsigned short* __restrict__ y, const float* __restrict__ bnp,
                               unsigned short* __restrict__ yn, int total8) {
    int i = blockIdx.x * blockDim.x + threadIdx.x;
    if (i >= total8) return;
    bf16x8 v = reinterpret_cast<const bf16x8*>(y)[i];
    int c0 = (i * 8) & 63;
    bf16x8 o;
    #pragma unroll
    for (int j = 0; j < 8; ++j) {
        float f = bf2f((unsigned short)v[j]) * bnp[c0 + j] + bnp[64 + c0 + j];
        f = fmaxf(f, 0.f);
        o[j] = (short)f2bf(f);
    }
    reinterpret_cast<bf16x8*>(yn)[i] = o;
}

// ---------------- final: BN2 + residual + ReLU -> f32 out, plus depth ----------------
__global__ void final_kernel(const unsigned short* __restrict__ y2, const float* __restrict__ x,
                             const float* __restrict__ bnp, const int* __restrict__ depth,
                             float* __restrict__ out, int total8, int n) {
    int i = blockIdx.x * blockDim.x + threadIdx.x;
    if (i == 0) out[(size_t)n * 64] = (float)depth[0];
    if (i >= total8) return;
    bf16x8 v = reinterpret_cast<const bf16x8*>(y2)[i];
    const float4* xp = reinterpret_cast<const float4*>(x) + (size_t)i * 2;
    float4 xa = xp[0], xbv = xp[1];
    int c0 = (i * 8) & 63;
    float r[8];
    #pragma unroll
    for (int j = 0; j < 8; ++j)
        r[j] = bf2f((unsigned short)v[j]) * bnp[c0 + j] + bnp[64 + c0 + j];
    r[0] += xa.x;  r[1] += xa.y;  r[2] += xa.z;  r[3] += xa.w;
    r[4] += xbv.x; r[5] += xbv.y; r[6] += xbv.z; r[7] += xbv.w;
    float4* op = reinterpret_cast<float4*>(out) + (size_t)i * 2;
    float4 o0 = {fmaxf(r[0], 0.f), fmaxf(r[1], 0.f), fmaxf(r[2], 0.f), fmaxf(r[3], 0.f)};
    float4 o1 = {fmaxf(r[4], 0.f), fmaxf(r[5], 0.f), fmaxf(r[6], 0.f), fmaxf(r[7], 0.f)};
    op[0] = o0;
    op[1] = o1;
}

extern "C" void kernel_launch(void* const* d_in, const int* in_sizes, int n_in,
                              void* d_out, int out_size, void* d_ws, size_t ws_size,
                              hipStream_t stream) {
    const float* x     = (const float*)d_in[0];
    const int*   neigh = (const int*)d_in[1];
    const int*   depth = (const int*)d_in[2];
    const float* W1    = (const float*)d_in[3];
    const float* g1    = (const float*)d_in[4];
    const float* b1    = (const float*)d_in[5];
    const float* W2    = (const float*)d_in[6];
    const float* g2    = (const float*)d_in[7];
    const float* b2    = (const float*)d_in[8];
    float* out = (float*)d_out;

    const int n      = in_sizes[0] / 64;   // 200000
    const int total8 = in_sizes[0] / 8;    // N*C/8
    const int nb     = (n + 63) / 64;      // conv grid (3125)

    char* ws = (char*)d_ws;
    size_t off = 0;
    auto carve = [&](size_t bytes) -> char* {
        char* p = ws + off;
        off += (bytes + 255) & ~((size_t)255);
        return p;
    };
    unsigned short* bufA = (unsigned short*)carve((size_t)n * 64 * 2); // xb, later y1n
    unsigned short* bufB = (unsigned short*)carve((size_t)n * 64 * 2); // y1, later y2
    unsigned short* w1t  = (unsigned short*)carve(27 * 4096 * 2);
    unsigned short* w2t  = (unsigned short*)carve(27 * 4096 * 2);
    float*          pS   = (float*)carve((size_t)nb * 64 * 4);
    float*          pQ   = (float*)carve((size_t)nb * 64 * 4);
    float*          bnp1 = (float*)carve(128 * 4);
    float*          bnp2 = (float*)carve(128 * 4);

    const int gx   = (total8 + 255) / 256;
    const int gw   = (2 * 27 * 4096 + 255) / 256;
    const float invN = 1.0f / (float)n;

    cvt_xw_kernel<<<gx + gw, 256, 0, stream>>>(x, bufA, total8, gx, W1, W2, w1t, w2t);

    conv_mfma<<<nb, 256, 0, stream>>>(bufA, neigh, w1t, bufB, pS, pQ, n);
    bn_stats_kernel<<<64, 256, 0, stream>>>(pS, pQ, g1, b1, bnp1, nb, invN);
    bn_relu_kernel<<<gx, 256, 0, stream>>>(bufB, bnp1, bufA, total8);

    conv_mfma<<<nb, 256, 0, stream>>>(bufA, neigh, w2t, bufB, pS, pQ, n);
    bn_stats_kernel<<<64, 256, 0, stream>>>(pS, pQ, g2, b2, bnp2, nb, invN);
    final_kernel<<<gx, 256, 0, stream>>>(bufB, x, bnp2, depth, out, total8, n);
}